// Round 4
// baseline (11271.295 us; speedup 1.0000x reference)
//
#include <hip/hip_runtime.h>

#define HDIM 64
#define STEPS 3

// ---------------- embed: x[i] = emb[tokens[i]] ----------------
__global__ __launch_bounds__(256) void k_embed(const int* __restrict__ tokens,
                                               const float* __restrict__ emb,
                                               float* __restrict__ x, int n) {
  int i = blockIdx.x * 256 + threadIdx.x;
  if (i < n * HDIM) {
    int node = i >> 6;
    int h = i & 63;
    x[i] = emb[tokens[node] * HDIM + h];
  }
}

// ---------------- one-time: transpose GRU weights into [k][3H] layout ----------------
__global__ __launch_bounds__(256) void k_wt(const float* __restrict__ w_ih,
                                            const float* __restrict__ w_hh,
                                            float* __restrict__ wiT,
                                            float* __restrict__ whT) {
  int t = blockIdx.x * 256 + threadIdx.x;
  if (t < HDIM * 3 * HDIM) {
    int k = t / (3 * HDIM);
    int j = t % (3 * HDIM);
    wiT[t] = w_ih[j * HDIM + k];
    whT[t] = w_hh[j * HDIM + k];
  }
}

// ---------------- CSR build: histogram of dst ----------------
__global__ __launch_bounds__(256) void k_hist(const int* __restrict__ dsts,
                                              int* __restrict__ deg, int ne) {
  int e = blockIdx.x * 256 + threadIdx.x;
  if (e < ne) atomicAdd(&deg[dsts[e]], 1);
}

// ---------------- CSR build: exclusive scan of deg -> rowptr (single block) ----------------
__global__ __launch_bounds__(1024) void k_scan(const int* __restrict__ deg,
                                               int* __restrict__ rowptr, int n) {
  __shared__ int part[1024];
  const int t = threadIdx.x;
  const int c = (n + 1023) >> 10;
  int lo = t * c;
  int hi = lo + c; if (hi > n) hi = n; if (lo > n) lo = n;
  int s = 0;
  for (int i = lo; i < hi; ++i) s += deg[i];
  part[t] = s;
  __syncthreads();
  for (int off = 1; off < 1024; off <<= 1) {
    int v = (t >= off) ? part[t - off] : 0;
    __syncthreads();
    part[t] += v;
    __syncthreads();
  }
  int run = (t == 0) ? 0 : part[t - 1];
  for (int i = lo; i < hi; ++i) {
    rowptr[i] = run;
    run += deg[i];
  }
  if (t == 1023) rowptr[n] = part[1023];
}

// ---------------- CSR build: fill edge source ids bucketed by dst ----------------
__global__ __launch_bounds__(256) void k_fill(const int* __restrict__ srcs,
                                              const int* __restrict__ dsts,
                                              int* __restrict__ cursor,
                                              int* __restrict__ eidx, int ne) {
  int e = blockIdx.x * 256 + threadIdx.x;
  if (e < ne) {
    int d = dsts[e];
    int p = atomicAdd(&cursor[d], 1);
    eidx[p] = srcs[e];
  }
}

// ---------------- m = x @ W  (W row-major [k][j]); 4 rows per wave ----------------
__global__ __launch_bounds__(256) void k_xform(const float* __restrict__ x,
                                               const float* __restrict__ W,
                                               float* __restrict__ m, int n) {
  __shared__ float Ws[HDIM * HDIM];
  for (int t = threadIdx.x; t < HDIM * HDIM; t += 256) Ws[t] = W[t];
  __syncthreads();
  const int lane = threadIdx.x & 63;
  const int wid = threadIdx.x >> 6;
  int g = blockIdx.x * 4 + wid;  // group of 4 rows
  int row0 = g * 4;
  if (row0 >= n) return;
  float xv[4], acc[4];
#pragma unroll
  for (int i = 0; i < 4; ++i) {
    int r = row0 + i;
    xv[i] = (r < n) ? x[r * HDIM + lane] : 0.f;
    acc[i] = 0.f;
  }
#pragma unroll
  for (int k = 0; k < HDIM; ++k) {
    float w = Ws[k * HDIM + lane];
#pragma unroll
    for (int i = 0; i < 4; ++i) acc[i] = fmaf(__shfl(xv[i], k), w, acc[i]);
  }
#pragma unroll
  for (int i = 0; i < 4; ++i) {
    int r = row0 + i;
    if (r < n) m[r * HDIM + lane] = acc[i];
  }
}

// ---------------- agg[d] = sum over CSR segment of m[src] (no atomics) ----------------
__global__ __launch_bounds__(256) void k_gather(const int* __restrict__ rowptr,
                                                const int* __restrict__ eidx,
                                                const float* __restrict__ m,
                                                float* __restrict__ agg, int n) {
  const int lane = threadIdx.x & 63;
  const int wid = threadIdx.x >> 6;
  int node = blockIdx.x * 4 + wid;
  if (node >= n) return;
  int lo = rowptr[node], hi = rowptr[node + 1];
  float acc = 0.f;
  int e = lo;
  for (; e + 4 <= hi; e += 4) {
    int s0 = eidx[e], s1 = eidx[e + 1], s2 = eidx[e + 2], s3 = eidx[e + 3];
    float v0 = m[s0 * HDIM + lane];
    float v1 = m[s1 * HDIM + lane];
    float v2 = m[s2 * HDIM + lane];
    float v3 = m[s3 * HDIM + lane];
    acc += (v0 + v1) + (v2 + v3);
  }
  for (; e < hi; ++e) acc += m[eidx[e] * HDIM + lane];
  agg[node * HDIM + lane] = acc;
}

// ---------------- GRU cell: x = GRU(agg, x) ----------------
// 512 threads = 8 waves; 96KB LDS -> 1 block/CU, VGPR cap 256 (no spill).
// 4 nodes per wave, persistent grid-stride; __shfl broadcast (proven in R2).
__global__ __launch_bounds__(512, 2) void k_gru(const float* __restrict__ agg,
                                                float* __restrict__ x,
                                                const float* __restrict__ wiT_g,
                                                const float* __restrict__ whT_g,
                                                const float* __restrict__ b_ih,
                                                const float* __restrict__ b_hh,
                                                int n) {
  __shared__ float wiT[HDIM * 3 * HDIM];  // [k][j] j in 0..191
  __shared__ float whT[HDIM * 3 * HDIM];
  for (int t = threadIdx.x; t < HDIM * 3 * HDIM; t += 512) {
    wiT[t] = wiT_g[t];
    whT[t] = whT_g[t];
  }
  __syncthreads();

  const int lane = threadIdx.x & 63;
  const int wid = threadIdx.x >> 6;  // 0..7
  const float Br = b_ih[lane] + b_hh[lane];
  const float Bz = b_ih[HDIM + lane] + b_hh[HDIM + lane];
  const float Bin = b_ih[2 * HDIM + lane];
  const float Bhn = b_hh[2 * HDIM + lane];

  const int NG = (n + 3) >> 2;
  const int stride = gridDim.x * 8;

  for (int g = blockIdx.x * 8 + wid; g < NG; g += stride) {
    const int node0 = g * 4;
    float av[4], xv[4];
#pragma unroll
    for (int i = 0; i < 4; ++i) {
      int node = node0 + i;
      bool ok = (node < n);
      av[i] = ok ? agg[node * HDIM + lane] : 0.f;
      xv[i] = ok ? x[node * HDIM + lane] : 0.f;
    }
    float ar[4] = {0, 0, 0, 0}, az[4] = {0, 0, 0, 0}, an[4] = {0, 0, 0, 0};
    float hr[4] = {0, 0, 0, 0}, hz[4] = {0, 0, 0, 0}, hn[4] = {0, 0, 0, 0};
#pragma unroll
    for (int k = 0; k < HDIM; ++k) {
      const float wr = wiT[k * 192 + lane];
      const float wz = wiT[k * 192 + 64 + lane];
      const float wn = wiT[k * 192 + 128 + lane];
      const float vr = whT[k * 192 + lane];
      const float vz = whT[k * 192 + 64 + lane];
      const float vn = whT[k * 192 + 128 + lane];
#pragma unroll
      for (int i = 0; i < 4; ++i) {
        const float a = __shfl(av[i], k);
        const float h = __shfl(xv[i], k);
        ar[i] = fmaf(a, wr, ar[i]);
        az[i] = fmaf(a, wz, az[i]);
        an[i] = fmaf(a, wn, an[i]);
        hr[i] = fmaf(h, vr, hr[i]);
        hz[i] = fmaf(h, vz, hz[i]);
        hn[i] = fmaf(h, vn, hn[i]);
      }
    }
#pragma unroll
    for (int i = 0; i < 4; ++i) {
      int node = node0 + i;
      if (node < n) {
        float r = 1.f / (1.f + __expf(-(ar[i] + hr[i] + Br)));
        float z = 1.f / (1.f + __expf(-(az[i] + hz[i] + Bz)));
        float nn = tanhf((an[i] + Bin) + r * (hn[i] + Bhn));
        x[node * HDIM + lane] = (1.f - z) * nn + z * xv[i];
      }
    }
  }
}

// ---------------- per-graph mean pool of relu(x); batch sorted ----------------
__device__ __forceinline__ int lower_bound_i(const int* __restrict__ a, int n, int v) {
  int lo = 0, hi = n;
  while (lo < hi) {
    int mid = (lo + hi) >> 1;
    if (a[mid] < v) lo = mid + 1; else hi = mid;
  }
  return lo;
}

__global__ __launch_bounds__(256) void k_pool(const float* __restrict__ x,
                                              const int* __restrict__ batch,
                                              float* __restrict__ pooled,
                                              int n) {
  int g = blockIdx.x;
  int lo = lower_bound_i(batch, n, g);
  int hi = lower_bound_i(batch, n, g + 1);
  const int lane = threadIdx.x & 63;
  const int w = threadIdx.x >> 6;  // 0..3
  float acc = 0.f;
  for (int i = lo + w; i < hi; i += 4) {
    acc += fmaxf(x[i * HDIM + lane], 0.f);
  }
  __shared__ float red[4][HDIM];
  red[w][lane] = acc;
  __syncthreads();
  if (w == 0) {
    float s = red[0][lane] + red[1][lane] + red[2][lane] + red[3][lane];
    float cnt = (float)(hi - lo);
    pooled[g * HDIM + lane] = s / fmaxf(cnt, 1.f);
  }
}

// ---------------- head ----------------
__global__ __launch_bounds__(256) void k_head(const float* __restrict__ pooled,
                                              const float* __restrict__ lin1_w,
                                              const float* __restrict__ lin1_b,
                                              const float* __restrict__ lout_w,
                                              const float* __restrict__ lout_b,
                                              float* __restrict__ out, int G) {
  __shared__ float P[128 * HDIM];
  __shared__ float W1T[HDIM * HDIM];  // [k][j]
  __shared__ float H1[128 * HDIM];
  for (int t = threadIdx.x; t < G * HDIM; t += 256) P[t] = pooled[t];
  for (int t = threadIdx.x; t < HDIM * HDIM; t += 256) {
    int j = t & 63, k = t >> 6;
    W1T[k * HDIM + j] = lin1_w[j * HDIM + k];
  }
  __syncthreads();
  for (int idx = threadIdx.x; idx < G * HDIM; idx += 256) {
    int g = idx >> 6, j = idx & 63;
    float acc = lin1_b[j];
#pragma unroll
    for (int k = 0; k < HDIM; ++k) acc = fmaf(P[g * HDIM + k], W1T[k * HDIM + j], acc);
    H1[idx] = fmaxf(acc, 0.f);
  }
  __syncthreads();
  for (int idx = threadIdx.x; idx < G * 2; idx += 256) {
    int g = idx >> 1, c = idx & 1;
    float acc = lout_b[c];
#pragma unroll
    for (int j = 0; j < HDIM; ++j) acc = fmaf(H1[g * HDIM + j], lout_w[c * HDIM + j], acc);
    out[idx] = acc;
  }
}

extern "C" void kernel_launch(void* const* d_in, const int* in_sizes, int n_in,
                              void* d_out, int out_size, void* d_ws, size_t ws_size,
                              hipStream_t stream) {
  const int* tokens   = (const int*)d_in[0];
  const int* edge_idx = (const int*)d_in[1];
  const int* batch    = (const int*)d_in[2];
  const float* emb    = (const float*)d_in[3];
  const float* ggnn_w = (const float*)d_in[4];
  const float* w_ih   = (const float*)d_in[5];
  const float* w_hh   = (const float*)d_in[6];
  const float* b_ih   = (const float*)d_in[7];
  const float* b_hh   = (const float*)d_in[8];
  const float* lin1_w = (const float*)d_in[9];
  const float* lin1_b = (const float*)d_in[10];
  const float* lout_w = (const float*)d_in[11];
  const float* lout_b = (const float*)d_in[12];

  const int N = in_sizes[0];
  const int E = in_sizes[1] / 2;
  const int G = out_size / 2;

  const int* srcs = edge_idx;
  const int* dsts = edge_idx + E;

  char* ws = (char*)d_ws;
  size_t off = 0;
  auto take = [&](size_t nbytes) -> char* {
    char* p = ws + off;
    off += (nbytes + 255) & ~(size_t)255;
    return p;
  };
  size_t rowBytes = (size_t)N * HDIM * sizeof(float);
  float* x      = (float*)take(rowBytes);
  float* m      = (float*)take(rowBytes);
  float* agg    = (float*)take(rowBytes);
  float* pooled = (float*)take((size_t)G * HDIM * sizeof(float));
  float* wiT_g  = (float*)take(HDIM * 3 * HDIM * sizeof(float));
  float* whT_g  = (float*)take(HDIM * 3 * HDIM * sizeof(float));
  int* rowptr   = (int*)take((size_t)(N + 1) * sizeof(int));
  int* cursor   = (int*)take((size_t)N * sizeof(int));  // also used as deg
  int* eidx     = (int*)take((size_t)E * sizeof(int));

  // --- one-time precompute: transposed GRU weights + CSR by dst ---
  k_wt<<<(HDIM * 3 * HDIM + 255) / 256, 256, 0, stream>>>(w_ih, w_hh, wiT_g, whT_g);
  hipMemsetAsync(cursor, 0, (size_t)N * sizeof(int), stream);
  k_hist<<<(E + 255) / 256, 256, 0, stream>>>(dsts, cursor, E);
  k_scan<<<1, 1024, 0, stream>>>(cursor, rowptr, N);
  hipMemcpyAsync(cursor, rowptr, (size_t)N * sizeof(int), hipMemcpyDeviceToDevice, stream);
  k_fill<<<(E + 255) / 256, 256, 0, stream>>>(srcs, dsts, cursor, eidx, E);

  // --- embed ---
  k_embed<<<(N * HDIM + 255) / 256, 256, 0, stream>>>(tokens, emb, x, N);

  // --- GGNN steps ---
  for (int s = 0; s < STEPS; ++s) {
    const float* W = ggnn_w + (size_t)s * HDIM * HDIM;
    int xblocks = (N + 15) / 16;  // 4 waves * 4 rows
    k_xform<<<xblocks, 256, 0, stream>>>(x, W, m, N);
    int gblocks = (N + 3) / 4;    // 4 waves * 1 node
    k_gather<<<gblocks, 256, 0, stream>>>(rowptr, eidx, m, agg, N);
    k_gru<<<256, 512, 0, stream>>>(agg, x, wiT_g, whT_g, b_ih, b_hh, N);
  }

  k_pool<<<G, 256, 0, stream>>>(x, batch, pooled, N);
  k_head<<<1, 256, 0, stream>>>(pooled, lin1_w, lin1_b, lout_w, lout_b,
                                (float*)d_out, G);
}

// Round 5
// 741.645 us; speedup vs baseline: 15.1977x; 15.1977x over previous
//
#include <hip/hip_runtime.h>

#define HDIM 64
#define STEPS 3

// ---------------- embed: x[i] = emb[tokens[i]] ----------------
__global__ __launch_bounds__(256) void k_embed(const int* __restrict__ tokens,
                                               const float* __restrict__ emb,
                                               float* __restrict__ x, int n) {
  int i = blockIdx.x * 256 + threadIdx.x;
  if (i < n * HDIM) {
    int node = i >> 6;
    int h = i & 63;
    x[i] = emb[tokens[node] * HDIM + h];
  }
}

// ---------------- one-time: whT[k][j] = w_hh[j][k]  (j in 0..191) ----------------
__global__ __launch_bounds__(256) void k_whT(const float* __restrict__ w_hh,
                                             float* __restrict__ whT) {
  int t = blockIdx.x * 256 + threadIdx.x;
  if (t < HDIM * 3 * HDIM) {
    int k = t / (3 * HDIM);
    int j = t % (3 * HDIM);
    whT[t] = w_hh[j * HDIM + k];
  }
}

// ---------------- one-time: wc[s][k][j] = sum_q W_s[k][q] * w_ih[j][q] ----------------
// (W_s @ w_ih^T), so gi = aggx @ wc[s]  ==  (aggx @ W_s) @ w_ih^T
__global__ __launch_bounds__(256) void k_wc(const float* __restrict__ W,
                                            const float* __restrict__ w_ih,
                                            float* __restrict__ wc) {
  int s = blockIdx.x;
  __shared__ float Ws[HDIM * HDIM];
  for (int t = threadIdx.x; t < HDIM * HDIM; t += 256) Ws[t] = W[s * HDIM * HDIM + t];
  __syncthreads();
  for (int o = threadIdx.x; o < HDIM * 3 * HDIM; o += 256) {
    int k = o / (3 * HDIM);
    int j = o % (3 * HDIM);
    float acc = 0.f;
#pragma unroll
    for (int q = 0; q < HDIM; ++q) acc = fmaf(Ws[k * HDIM + q], w_ih[j * HDIM + q], acc);
    wc[s * HDIM * 3 * HDIM + o] = acc;
  }
}

// ---------------- CSR build: histogram of dst ----------------
__global__ __launch_bounds__(256) void k_hist(const int* __restrict__ dsts,
                                              int* __restrict__ deg, int ne) {
  int e = blockIdx.x * 256 + threadIdx.x;
  if (e < ne) atomicAdd(&deg[dsts[e]], 1);
}

// ---------------- CSR build: exclusive scan of deg -> rowptr (single block) ----------------
__global__ __launch_bounds__(1024) void k_scan(const int* __restrict__ deg,
                                               int* __restrict__ rowptr, int n) {
  __shared__ int part[1024];
  const int t = threadIdx.x;
  const int c = (n + 1023) >> 10;
  int lo = t * c;
  int hi = lo + c; if (hi > n) hi = n; if (lo > n) lo = n;
  int s = 0;
  for (int i = lo; i < hi; ++i) s += deg[i];
  part[t] = s;
  __syncthreads();
  for (int off = 1; off < 1024; off <<= 1) {
    int v = (t >= off) ? part[t - off] : 0;
    __syncthreads();
    part[t] += v;
    __syncthreads();
  }
  int run = (t == 0) ? 0 : part[t - 1];
  for (int i = lo; i < hi; ++i) {
    rowptr[i] = run;
    run += deg[i];
  }
  if (t == 1023) rowptr[n] = part[1023];
}

// ---------------- CSR build: fill edge source ids bucketed by dst ----------------
__global__ __launch_bounds__(256) void k_fill(const int* __restrict__ srcs,
                                              const int* __restrict__ dsts,
                                              int* __restrict__ cursor,
                                              int* __restrict__ eidx, int ne) {
  int e = blockIdx.x * 256 + threadIdx.x;
  if (e < ne) {
    int d = dsts[e];
    int p = atomicAdd(&cursor[d], 1);
    eidx[p] = srcs[e];
  }
}

// ---------------- aggx[d] = sum over CSR segment of x[src] (no atomics) ----------------
__global__ __launch_bounds__(256) void k_gather(const int* __restrict__ rowptr,
                                                const int* __restrict__ eidx,
                                                const float* __restrict__ x,
                                                float* __restrict__ agg, int n) {
  const int lane = threadIdx.x & 63;
  const int wid = threadIdx.x >> 6;
  int node = blockIdx.x * 4 + wid;
  if (node >= n) return;
  int lo = rowptr[node], hi = rowptr[node + 1];
  float acc = 0.f;
  int e = lo;
  for (; e + 4 <= hi; e += 4) {
    int s0 = eidx[e], s1 = eidx[e + 1], s2 = eidx[e + 2], s3 = eidx[e + 3];
    float v0 = x[s0 * HDIM + lane];
    float v1 = x[s1 * HDIM + lane];
    float v2 = x[s2 * HDIM + lane];
    float v3 = x[s3 * HDIM + lane];
    acc += (v0 + v1) + (v2 + v3);
  }
  for (; e < hi; ++e) acc += x[eidx[e] * HDIM + lane];
  agg[node * HDIM + lane] = acc;
}

// ---------------- GRU cell: x = GRU(aggx @ Wc, x) ----------------
// 512 threads = 8 waves; 96KB LDS -> 1 block/CU. 4 nodes per wave, persistent
// grid-stride; __shfl broadcast. k-loop unroll LIMITED to 4 (full unroll spilled
// to scratch in R2/R4: 4-5 GB of FETCH at <1% VALUBusy).
__global__ __launch_bounds__(512, 2) void k_gru(const float* __restrict__ agg,
                                                float* __restrict__ x,
                                                const float* __restrict__ wc_g,
                                                const float* __restrict__ whT_g,
                                                const float* __restrict__ b_ih,
                                                const float* __restrict__ b_hh,
                                                int n) {
  __shared__ float wiT[HDIM * 3 * HDIM];  // step-combined input weights [k][192]
  __shared__ float whT[HDIM * 3 * HDIM];  // hidden weights [k][192]
  for (int t = threadIdx.x; t < HDIM * 3 * HDIM; t += 512) {
    wiT[t] = wc_g[t];
    whT[t] = whT_g[t];
  }
  __syncthreads();

  const int lane = threadIdx.x & 63;
  const int wid = threadIdx.x >> 6;  // 0..7
  const float Br = b_ih[lane] + b_hh[lane];
  const float Bz = b_ih[HDIM + lane] + b_hh[HDIM + lane];
  const float Bin = b_ih[2 * HDIM + lane];
  const float Bhn = b_hh[2 * HDIM + lane];

  const int NG = (n + 3) >> 2;
  const int stride = gridDim.x * 8;

  for (int g = blockIdx.x * 8 + wid; g < NG; g += stride) {
    const int node0 = g * 4;
    float av[4], xv[4];
#pragma unroll
    for (int i = 0; i < 4; ++i) {
      int node = node0 + i;
      bool ok = (node < n);
      av[i] = ok ? agg[node * HDIM + lane] : 0.f;
      xv[i] = ok ? x[node * HDIM + lane] : 0.f;
    }
    float ar[4] = {0, 0, 0, 0}, az[4] = {0, 0, 0, 0}, an[4] = {0, 0, 0, 0};
    float hr[4] = {0, 0, 0, 0}, hz[4] = {0, 0, 0, 0}, hn[4] = {0, 0, 0, 0};
#pragma unroll 4
    for (int k = 0; k < HDIM; ++k) {
      const float wr = wiT[k * 192 + lane];
      const float wz = wiT[k * 192 + 64 + lane];
      const float wn = wiT[k * 192 + 128 + lane];
      const float vr = whT[k * 192 + lane];
      const float vz = whT[k * 192 + 64 + lane];
      const float vn = whT[k * 192 + 128 + lane];
#pragma unroll
      for (int i = 0; i < 4; ++i) {
        const float a = __shfl(av[i], k);
        const float h = __shfl(xv[i], k);
        ar[i] = fmaf(a, wr, ar[i]);
        az[i] = fmaf(a, wz, az[i]);
        an[i] = fmaf(a, wn, an[i]);
        hr[i] = fmaf(h, vr, hr[i]);
        hz[i] = fmaf(h, vz, hz[i]);
        hn[i] = fmaf(h, vn, hn[i]);
      }
    }
#pragma unroll
    for (int i = 0; i < 4; ++i) {
      int node = node0 + i;
      if (node < n) {
        float r = 1.f / (1.f + __expf(-(ar[i] + hr[i] + Br)));
        float z = 1.f / (1.f + __expf(-(az[i] + hz[i] + Bz)));
        float nn = tanhf((an[i] + Bin) + r * (hn[i] + Bhn));
        x[node * HDIM + lane] = (1.f - z) * nn + z * xv[i];
      }
    }
  }
}

// ---------------- per-graph mean pool of relu(x); batch sorted ----------------
__device__ __forceinline__ int lower_bound_i(const int* __restrict__ a, int n, int v) {
  int lo = 0, hi = n;
  while (lo < hi) {
    int mid = (lo + hi) >> 1;
    if (a[mid] < v) lo = mid + 1; else hi = mid;
  }
  return lo;
}

__global__ __launch_bounds__(256) void k_pool(const float* __restrict__ x,
                                              const int* __restrict__ batch,
                                              float* __restrict__ pooled,
                                              int n) {
  int g = blockIdx.x;
  int lo = lower_bound_i(batch, n, g);
  int hi = lower_bound_i(batch, n, g + 1);
  const int lane = threadIdx.x & 63;
  const int w = threadIdx.x >> 6;  // 0..3
  float acc = 0.f;
  for (int i = lo + w; i < hi; i += 4) {
    acc += fmaxf(x[i * HDIM + lane], 0.f);
  }
  __shared__ float red[4][HDIM];
  red[w][lane] = acc;
  __syncthreads();
  if (w == 0) {
    float s = red[0][lane] + red[1][lane] + red[2][lane] + red[3][lane];
    float cnt = (float)(hi - lo);
    pooled[g * HDIM + lane] = s / fmaxf(cnt, 1.f);
  }
}

// ---------------- head ----------------
__global__ __launch_bounds__(256) void k_head(const float* __restrict__ pooled,
                                              const float* __restrict__ lin1_w,
                                              const float* __restrict__ lin1_b,
                                              const float* __restrict__ lout_w,
                                              const float* __restrict__ lout_b,
                                              float* __restrict__ out, int G) {
  __shared__ float P[128 * HDIM];
  __shared__ float W1T[HDIM * HDIM];  // [k][j]
  __shared__ float H1[128 * HDIM];
  for (int t = threadIdx.x; t < G * HDIM; t += 256) P[t] = pooled[t];
  for (int t = threadIdx.x; t < HDIM * HDIM; t += 256) {
    int j = t & 63, k = t >> 6;
    W1T[k * HDIM + j] = lin1_w[j * HDIM + k];
  }
  __syncthreads();
  for (int idx = threadIdx.x; idx < G * HDIM; idx += 256) {
    int g = idx >> 6, j = idx & 63;
    float acc = lin1_b[j];
#pragma unroll
    for (int k = 0; k < HDIM; ++k) acc = fmaf(P[g * HDIM + k], W1T[k * HDIM + j], acc);
    H1[idx] = fmaxf(acc, 0.f);
  }
  __syncthreads();
  for (int idx = threadIdx.x; idx < G * 2; idx += 256) {
    int g = idx >> 1, c = idx & 1;
    float acc = lout_b[c];
#pragma unroll
    for (int j = 0; j < HDIM; ++j) acc = fmaf(H1[g * HDIM + j], lout_w[c * HDIM + j], acc);
    out[idx] = acc;
  }
}

extern "C" void kernel_launch(void* const* d_in, const int* in_sizes, int n_in,
                              void* d_out, int out_size, void* d_ws, size_t ws_size,
                              hipStream_t stream) {
  const int* tokens   = (const int*)d_in[0];
  const int* edge_idx = (const int*)d_in[1];
  const int* batch    = (const int*)d_in[2];
  const float* emb    = (const float*)d_in[3];
  const float* ggnn_w = (const float*)d_in[4];
  const float* w_ih   = (const float*)d_in[5];
  const float* w_hh   = (const float*)d_in[6];
  const float* b_ih   = (const float*)d_in[7];
  const float* b_hh   = (const float*)d_in[8];
  const float* lin1_w = (const float*)d_in[9];
  const float* lin1_b = (const float*)d_in[10];
  const float* lout_w = (const float*)d_in[11];
  const float* lout_b = (const float*)d_in[12];

  const int N = in_sizes[0];
  const int E = in_sizes[1] / 2;
  const int G = out_size / 2;

  const int* srcs = edge_idx;
  const int* dsts = edge_idx + E;

  char* ws = (char*)d_ws;
  size_t off = 0;
  auto take = [&](size_t nbytes) -> char* {
    char* p = ws + off;
    off += (nbytes + 255) & ~(size_t)255;
    return p;
  };
  size_t rowBytes = (size_t)N * HDIM * sizeof(float);
  float* x      = (float*)take(rowBytes);
  float* agg    = (float*)take(rowBytes);
  float* pooled = (float*)take((size_t)G * HDIM * sizeof(float));
  float* whT_g  = (float*)take(HDIM * 3 * HDIM * sizeof(float));
  float* wc_g   = (float*)take((size_t)STEPS * HDIM * 3 * HDIM * sizeof(float));
  int* rowptr   = (int*)take((size_t)(N + 1) * sizeof(int));
  int* cursor   = (int*)take((size_t)N * sizeof(int));  // also used as deg
  int* eidx     = (int*)take((size_t)E * sizeof(int));

  // --- one-time precompute: whT, combined input weights, CSR by dst ---
  k_whT<<<(HDIM * 3 * HDIM + 255) / 256, 256, 0, stream>>>(w_hh, whT_g);
  k_wc<<<STEPS, 256, 0, stream>>>(ggnn_w, w_ih, wc_g);
  hipMemsetAsync(cursor, 0, (size_t)N * sizeof(int), stream);
  k_hist<<<(E + 255) / 256, 256, 0, stream>>>(dsts, cursor, E);
  k_scan<<<1, 1024, 0, stream>>>(cursor, rowptr, N);
  hipMemcpyAsync(cursor, rowptr, (size_t)N * sizeof(int), hipMemcpyDeviceToDevice, stream);
  k_fill<<<(E + 255) / 256, 256, 0, stream>>>(srcs, dsts, cursor, eidx, E);

  // --- embed ---
  k_embed<<<(N * HDIM + 255) / 256, 256, 0, stream>>>(tokens, emb, x, N);

  // --- GGNN steps: gather raw x, then fused (aggx@Wc) GRU ---
  for (int s = 0; s < STEPS; ++s) {
    int gblocks = (N + 3) / 4;  // 4 waves * 1 node
    k_gather<<<gblocks, 256, 0, stream>>>(rowptr, eidx, x, agg, N);
    k_gru<<<256, 512, 0, stream>>>(agg, x, wc_g + (size_t)s * HDIM * 3 * HDIM,
                                   whT_g, b_ih, b_hh, N);
  }

  k_pool<<<G, 256, 0, stream>>>(x, batch, pooled, N);
  k_head<<<1, 256, 0, stream>>>(pooled, lin1_w, lin1_b, lout_w, lout_b,
                                (float*)d_out, G);
}

// Round 6
// 734.860 us; speedup vs baseline: 15.3380x; 1.0092x over previous
//
#include <hip/hip_runtime.h>

#define HDIM 64
#define STEPS 3

// ---------------- embed: x[i] = emb[tokens[i]] ----------------
__global__ __launch_bounds__(256) void k_embed(const int* __restrict__ tokens,
                                               const float* __restrict__ emb,
                                               float* __restrict__ x, int n) {
  int i = blockIdx.x * 256 + threadIdx.x;
  if (i < n * HDIM) {
    int node = i >> 6;
    int h = i & 63;
    x[i] = emb[tokens[node] * HDIM + h];
  }
}

// ---------------- one-time: whT[k][j] = w_hh[j][k]  (j in 0..191) ----------------
__global__ __launch_bounds__(256) void k_whT(const float* __restrict__ w_hh,
                                             float* __restrict__ whT) {
  int t = blockIdx.x * 256 + threadIdx.x;
  if (t < HDIM * 3 * HDIM) {
    int k = t / (3 * HDIM);
    int j = t % (3 * HDIM);
    whT[t] = w_hh[j * HDIM + k];
  }
}

// ---------------- one-time: wc[s][k][j] = sum_q W_s[k][q] * w_ih[j][q] ----------------
__global__ __launch_bounds__(256) void k_wc(const float* __restrict__ W,
                                            const float* __restrict__ w_ih,
                                            float* __restrict__ wc) {
  int s = blockIdx.x;
  __shared__ float Ws[HDIM * HDIM];
  for (int t = threadIdx.x; t < HDIM * HDIM; t += 256) Ws[t] = W[s * HDIM * HDIM + t];
  __syncthreads();
  for (int o = threadIdx.x; o < HDIM * 3 * HDIM; o += 256) {
    int k = o / (3 * HDIM);
    int j = o % (3 * HDIM);
    float acc = 0.f;
#pragma unroll
    for (int q = 0; q < HDIM; ++q) acc = fmaf(Ws[k * HDIM + q], w_ih[j * HDIM + q], acc);
    wc[s * HDIM * 3 * HDIM + o] = acc;
  }
}

// ---------------- CSR build: histogram of dst ----------------
__global__ __launch_bounds__(256) void k_hist(const int* __restrict__ dsts,
                                              int* __restrict__ deg, int ne) {
  int e = blockIdx.x * 256 + threadIdx.x;
  if (e < ne) atomicAdd(&deg[dsts[e]], 1);
}

// ---------------- CSR build: exclusive scan of deg -> rowptr (single block) ----------------
__global__ __launch_bounds__(1024) void k_scan(const int* __restrict__ deg,
                                               int* __restrict__ rowptr, int n) {
  __shared__ int part[1024];
  const int t = threadIdx.x;
  const int c = (n + 1023) >> 10;
  int lo = t * c;
  int hi = lo + c; if (hi > n) hi = n; if (lo > n) lo = n;
  int s = 0;
  for (int i = lo; i < hi; ++i) s += deg[i];
  part[t] = s;
  __syncthreads();
  for (int off = 1; off < 1024; off <<= 1) {
    int v = (t >= off) ? part[t - off] : 0;
    __syncthreads();
    part[t] += v;
    __syncthreads();
  }
  int run = (t == 0) ? 0 : part[t - 1];
  for (int i = lo; i < hi; ++i) {
    rowptr[i] = run;
    run += deg[i];
  }
  if (t == 1023) rowptr[n] = part[1023];
}

// ---------------- CSR build: fill edge source ids bucketed by dst ----------------
__global__ __launch_bounds__(256) void k_fill(const int* __restrict__ srcs,
                                              const int* __restrict__ dsts,
                                              int* __restrict__ cursor,
                                              int* __restrict__ eidx, int ne) {
  int e = blockIdx.x * 256 + threadIdx.x;
  if (e < ne) {
    int d = dsts[e];
    int p = atomicAdd(&cursor[d], 1);
    eidx[p] = srcs[e];
  }
}

// ---------------- aggx[d] = sum over CSR segment of x[src] (no atomics) ----------------
__global__ __launch_bounds__(256) void k_gather(const int* __restrict__ rowptr,
                                                const int* __restrict__ eidx,
                                                const float* __restrict__ x,
                                                float* __restrict__ agg, int n) {
  const int lane = threadIdx.x & 63;
  const int wid = threadIdx.x >> 6;
  int node = blockIdx.x * 4 + wid;
  if (node >= n) return;
  int lo = rowptr[node], hi = rowptr[node + 1];
  float acc = 0.f;
  int e = lo;
  for (; e + 8 <= hi; e += 8) {
    int s0 = eidx[e],     s1 = eidx[e + 1], s2 = eidx[e + 2], s3 = eidx[e + 3];
    int s4 = eidx[e + 4], s5 = eidx[e + 5], s6 = eidx[e + 6], s7 = eidx[e + 7];
    float v0 = x[s0 * HDIM + lane];
    float v1 = x[s1 * HDIM + lane];
    float v2 = x[s2 * HDIM + lane];
    float v3 = x[s3 * HDIM + lane];
    float v4 = x[s4 * HDIM + lane];
    float v5 = x[s5 * HDIM + lane];
    float v6 = x[s6 * HDIM + lane];
    float v7 = x[s7 * HDIM + lane];
    acc += ((v0 + v1) + (v2 + v3)) + ((v4 + v5) + (v6 + v7));
  }
  for (; e < hi; ++e) acc += x[eidx[e] * HDIM + lane];
  agg[node * HDIM + lane] = acc;
}

// ---------------- GRU cell: x = GRU(aggx @ Wc, x) ----------------
// 512 threads = 8 waves; LDS only 48KB (wiT) -> 2 blocks/CU = 16 waves/CU.
// whT read from global (block-shared, coalesced, L1/L2-hot) - moves 3 of the
// 14 LDS-pipe ops per k-iter to the idle VMEM pipe. k-loop unroll 4 (full
// unroll spilled in R2/R4). __shfl broadcast (proven).
__global__ __launch_bounds__(512, 2) void k_gru(const float* __restrict__ agg,
                                                float* __restrict__ x,
                                                const float* __restrict__ wc_g,
                                                const float* __restrict__ whT_g,
                                                const float* __restrict__ b_ih,
                                                const float* __restrict__ b_hh,
                                                int n) {
  __shared__ float wiT[HDIM * 3 * HDIM];  // step-combined input weights [k][192]
  for (int t = threadIdx.x; t < HDIM * 3 * HDIM; t += 512) {
    wiT[t] = wc_g[t];
  }
  __syncthreads();

  const int lane = threadIdx.x & 63;
  const int wid = threadIdx.x >> 6;  // 0..7
  const float Br = b_ih[lane] + b_hh[lane];
  const float Bz = b_ih[HDIM + lane] + b_hh[HDIM + lane];
  const float Bin = b_ih[2 * HDIM + lane];
  const float Bhn = b_hh[2 * HDIM + lane];

  const int NG = (n + 3) >> 2;
  const int stride = gridDim.x * 8;

  for (int g = blockIdx.x * 8 + wid; g < NG; g += stride) {
    const int node0 = g * 4;
    float av[4], xv[4];
#pragma unroll
    for (int i = 0; i < 4; ++i) {
      int node = node0 + i;
      bool ok = (node < n);
      av[i] = ok ? agg[node * HDIM + lane] : 0.f;
      xv[i] = ok ? x[node * HDIM + lane] : 0.f;
    }
    float ar[4] = {0, 0, 0, 0}, az[4] = {0, 0, 0, 0}, an[4] = {0, 0, 0, 0};
    float hr[4] = {0, 0, 0, 0}, hz[4] = {0, 0, 0, 0}, hn[4] = {0, 0, 0, 0};
#pragma unroll 4
    for (int k = 0; k < HDIM; ++k) {
      const float vr = whT_g[k * 192 + lane];
      const float vz = whT_g[k * 192 + 64 + lane];
      const float vn = whT_g[k * 192 + 128 + lane];
      const float wr = wiT[k * 192 + lane];
      const float wz = wiT[k * 192 + 64 + lane];
      const float wn = wiT[k * 192 + 128 + lane];
#pragma unroll
      for (int i = 0; i < 4; ++i) {
        const float a = __shfl(av[i], k);
        const float h = __shfl(xv[i], k);
        ar[i] = fmaf(a, wr, ar[i]);
        az[i] = fmaf(a, wz, az[i]);
        an[i] = fmaf(a, wn, an[i]);
        hr[i] = fmaf(h, vr, hr[i]);
        hz[i] = fmaf(h, vz, hz[i]);
        hn[i] = fmaf(h, vn, hn[i]);
      }
    }
#pragma unroll
    for (int i = 0; i < 4; ++i) {
      int node = node0 + i;
      if (node < n) {
        float r = 1.f / (1.f + __expf(-(ar[i] + hr[i] + Br)));
        float z = 1.f / (1.f + __expf(-(az[i] + hz[i] + Bz)));
        float nn = tanhf((an[i] + Bin) + r * (hn[i] + Bhn));
        x[node * HDIM + lane] = (1.f - z) * nn + z * xv[i];
      }
    }
  }
}

// ---------------- per-graph mean pool of relu(x); batch sorted ----------------
__device__ __forceinline__ int lower_bound_i(const int* __restrict__ a, int n, int v) {
  int lo = 0, hi = n;
  while (lo < hi) {
    int mid = (lo + hi) >> 1;
    if (a[mid] < v) lo = mid + 1; else hi = mid;
  }
  return lo;
}

__global__ __launch_bounds__(256) void k_pool(const float* __restrict__ x,
                                              const int* __restrict__ batch,
                                              float* __restrict__ pooled,
                                              int n) {
  int g = blockIdx.x;
  int lo = lower_bound_i(batch, n, g);
  int hi = lower_bound_i(batch, n, g + 1);
  const int lane = threadIdx.x & 63;
  const int w = threadIdx.x >> 6;  // 0..3
  float acc = 0.f;
  for (int i = lo + w; i < hi; i += 4) {
    acc += fmaxf(x[i * HDIM + lane], 0.f);
  }
  __shared__ float red[4][HDIM];
  red[w][lane] = acc;
  __syncthreads();
  if (w == 0) {
    float s = red[0][lane] + red[1][lane] + red[2][lane] + red[3][lane];
    float cnt = (float)(hi - lo);
    pooled[g * HDIM + lane] = s / fmaxf(cnt, 1.f);
  }
}

// ---------------- head ----------------
__global__ __launch_bounds__(256) void k_head(const float* __restrict__ pooled,
                                              const float* __restrict__ lin1_w,
                                              const float* __restrict__ lin1_b,
                                              const float* __restrict__ lout_w,
                                              const float* __restrict__ lout_b,
                                              float* __restrict__ out, int G) {
  __shared__ float P[128 * HDIM];
  __shared__ float W1T[HDIM * HDIM];  // [k][j]
  __shared__ float H1[128 * HDIM];
  for (int t = threadIdx.x; t < G * HDIM; t += 256) P[t] = pooled[t];
  for (int t = threadIdx.x; t < HDIM * HDIM; t += 256) {
    int j = t & 63, k = t >> 6;
    W1T[k * HDIM + j] = lin1_w[j * HDIM + k];
  }
  __syncthreads();
  for (int idx = threadIdx.x; idx < G * HDIM; idx += 256) {
    int g = idx >> 6, j = idx & 63;
    float acc = lin1_b[j];
#pragma unroll
    for (int k = 0; k < HDIM; ++k) acc = fmaf(P[g * HDIM + k], W1T[k * HDIM + j], acc);
    H1[idx] = fmaxf(acc, 0.f);
  }
  __syncthreads();
  for (int idx = threadIdx.x; idx < G * 2; idx += 256) {
    int g = idx >> 1, c = idx & 1;
    float acc = lout_b[c];
#pragma unroll
    for (int j = 0; j < HDIM; ++j) acc = fmaf(H1[g * HDIM + j], lout_w[c * HDIM + j], acc);
    out[idx] = acc;
  }
}

extern "C" void kernel_launch(void* const* d_in, const int* in_sizes, int n_in,
                              void* d_out, int out_size, void* d_ws, size_t ws_size,
                              hipStream_t stream) {
  const int* tokens   = (const int*)d_in[0];
  const int* edge_idx = (const int*)d_in[1];
  const int* batch    = (const int*)d_in[2];
  const float* emb    = (const float*)d_in[3];
  const float* ggnn_w = (const float*)d_in[4];
  const float* w_ih   = (const float*)d_in[5];
  const float* w_hh   = (const float*)d_in[6];
  const float* b_ih   = (const float*)d_in[7];
  const float* b_hh   = (const float*)d_in[8];
  const float* lin1_w = (const float*)d_in[9];
  const float* lin1_b = (const float*)d_in[10];
  const float* lout_w = (const float*)d_in[11];
  const float* lout_b = (const float*)d_in[12];

  const int N = in_sizes[0];
  const int E = in_sizes[1] / 2;
  const int G = out_size / 2;

  const int* srcs = edge_idx;
  const int* dsts = edge_idx + E;

  char* ws = (char*)d_ws;
  size_t off = 0;
  auto take = [&](size_t nbytes) -> char* {
    char* p = ws + off;
    off += (nbytes + 255) & ~(size_t)255;
    return p;
  };
  size_t rowBytes = (size_t)N * HDIM * sizeof(float);
  float* x      = (float*)take(rowBytes);
  float* agg    = (float*)take(rowBytes);
  float* pooled = (float*)take((size_t)G * HDIM * sizeof(float));
  float* whT_g  = (float*)take(HDIM * 3 * HDIM * sizeof(float));
  float* wc_g   = (float*)take((size_t)STEPS * HDIM * 3 * HDIM * sizeof(float));
  int* rowptr   = (int*)take((size_t)(N + 1) * sizeof(int));
  int* cursor   = (int*)take((size_t)N * sizeof(int));  // also used as deg
  int* eidx     = (int*)take((size_t)E * sizeof(int));

  // --- one-time precompute: whT, combined input weights, CSR by dst ---
  k_whT<<<(HDIM * 3 * HDIM + 255) / 256, 256, 0, stream>>>(w_hh, whT_g);
  k_wc<<<STEPS, 256, 0, stream>>>(ggnn_w, w_ih, wc_g);
  hipMemsetAsync(cursor, 0, (size_t)N * sizeof(int), stream);
  k_hist<<<(E + 255) / 256, 256, 0, stream>>>(dsts, cursor, E);
  k_scan<<<1, 1024, 0, stream>>>(cursor, rowptr, N);
  hipMemcpyAsync(cursor, rowptr, (size_t)N * sizeof(int), hipMemcpyDeviceToDevice, stream);
  k_fill<<<(E + 255) / 256, 256, 0, stream>>>(srcs, dsts, cursor, eidx, E);

  // --- embed ---
  k_embed<<<(N * HDIM + 255) / 256, 256, 0, stream>>>(tokens, emb, x, N);

  // --- GGNN steps: gather raw x, then fused (aggx@Wc) GRU ---
  for (int s = 0; s < STEPS; ++s) {
    int gblocks = (N + 3) / 4;  // 4 waves * 1 node
    k_gather<<<gblocks, 256, 0, stream>>>(rowptr, eidx, x, agg, N);
    k_gru<<<512, 512, 0, stream>>>(agg, x, wc_g + (size_t)s * HDIM * 3 * HDIM,
                                   whT_g, b_ih, b_hh, N);
  }

  k_pool<<<G, 256, 0, stream>>>(x, batch, pooled, N);
  k_head<<<1, 256, 0, stream>>>(pooled, lin1_w, lin1_b, lout_w, lout_b,
                                (float*)d_out, G);
}